// Round 3
// baseline (154476.880 us; speedup 1.0000x reference)
//
#include <hip/hip_runtime.h>

#define T_LEN 1024
#define HID   128
#define G4    512
#define BCH   4
#define NG    128

typedef _Float16 h2_t __attribute__((ext_vector_type(2)));

__device__ __forceinline__ h2_t as_h2(unsigned int u) {
  union { unsigned int u; h2_t h; } c; c.u = u; return c.h;
}
__device__ __forceinline__ float fdot2(unsigned int a, unsigned int b, float c) {
  return __builtin_amdgcn_fdot2(as_h2(a), as_h2(b), c, false);
}

__device__ __forceinline__ float fsig(float v) {
  return __builtin_amdgcn_rcpf(1.0f + __expf(-v));
}
__device__ __forceinline__ float ftanh(float v) {
  float a = fabsf(v);
  float e = __expf(-2.0f * a);
  float t = (1.0f - e) * __builtin_amdgcn_rcpf(1.0f + e);
  return copysignf(t, v);
}
__device__ __forceinline__ float gact(float v, int gt) {
  return (gt == 2) ? ftanh(v) : fsig(v);
}

// ---------------------------------------------------------------------------
// Pack fp32 [512][128] weights -> fp16 half8 blocks, k-major:
// dst[(m*16 + k8)*512 + j] = uint4 of 8 halves {w[j][8k8 .. 8k8+7]}
// m: 0=Whh1, 1=Wih2, 2=Whh2
// ---------------------------------------------------------------------------
__global__ void __launch_bounds__(256) pack_w(
    const float* __restrict__ wa, const float* __restrict__ wb,
    const float* __restrict__ wc, uint4* __restrict__ dst) {
  int m = blockIdx.y;
  const float* src = (m == 0) ? wa : (m == 1) ? wb : wc;
  int idx = blockIdx.x * 256 + threadIdx.x;  // 0..8191
  int j  = idx & (G4 - 1);
  int k8 = idx >> 9;
  const float* s = src + (size_t)j * HID + k8 * 8;
  unsigned int r[4];
#pragma unroll
  for (int q = 0; q < 4; ++q) {
    h2_t h;
    h.x = (_Float16)s[2 * q];
    h.y = (_Float16)s[2 * q + 1];
    r[q] = __builtin_bit_cast(unsigned int, h);
  }
  dst[(size_t)(m * 16 + k8) * G4 + j] = make_uint4(r[0], r[1], r[2], r[3]);
}

__device__ __forceinline__ void store_out(const float4* h2buf, float wo0, float wo1,
                                          float bo, int tid, int b0,
                                          float* __restrict__ outp, int t) {
  float4 ha = h2buf[tid];
  float4 hb = h2buf[tid + 64];
  float p0 = wo0 * ha.x + wo1 * hb.x;
  float p1 = wo0 * ha.y + wo1 * hb.y;
  float p2 = wo0 * ha.z + wo1 * hb.z;
  float p3 = wo0 * ha.w + wo1 * hb.w;
#pragma unroll
  for (int off = 1; off < 64; off <<= 1) {
    p0 += __shfl_xor(p0, off, 64);
    p1 += __shfl_xor(p1, off, 64);
    p2 += __shfl_xor(p2, off, 64);
    p3 += __shfl_xor(p3, off, 64);
  }
  if (tid < BCH) {
    float v = (tid == 0) ? p0 : (tid == 1) ? p1 : (tid == 2) ? p2 : p3;
    outp[(size_t)(b0 + tid) * T_LEN + t] = v + bo;
  }
}

// ---------------------------------------------------------------------------
// fp16-weight streaming kernel. One WG per 4 batches. Thread tid owns gate
// row tid (both layers). h1/h2 in LDS as fp16 half2 (pairs of k), batch-major
// uint4: h[k2] = {half2(h[2k2],h[2k2+1]) for b=0..3}. Gates/c/x fp32.
// ---------------------------------------------------------------------------
__global__ void __launch_bounds__(512, 1) lstm_f16(
    const float* __restrict__ xin, const float* __restrict__ Wih1,
    const float* __restrict__ bih1, const float* __restrict__ bhh1,
    const uint4* __restrict__ wpk,
    const float* __restrict__ bih2, const float* __restrict__ bhh2,
    const float* __restrict__ Wout, const float* __restrict__ bout,
    float* __restrict__ outp)
{
  __shared__ float4 g1[G4];       // activated layer-1 gates (fp32, 4 batches)
  __shared__ float4 g2[G4];
  __shared__ float4 h2f[HID];     // fp32 copy of h2 for the output dot
  __shared__ uint4  h1h[64];      // fp16 h1: [k2] -> 4 batches of half2
  __shared__ uint4  h2h[64];
  __shared__ float  xb[2][BCH];

  const int tid = threadIdx.x;
  const int b0  = blockIdx.x * BCH;
  const int gt  = tid >> 7;
  const int u   = tid & (HID - 1);

  const float bias1 = bih1[tid] + bhh1[tid];
  const float bias2 = bih2[tid] + bhh2[tid];
  const float wi1   = Wih1[tid];
  float wo0 = 0.f, wo1 = 0.f, bo = 0.f;
  if (tid < 64) { wo0 = Wout[tid]; wo1 = Wout[tid + 64]; bo = bout[0]; }
  float4 c1 = make_float4(0.f, 0.f, 0.f, 0.f);
  float4 c2 = make_float4(0.f, 0.f, 0.f, 0.f);

  if (tid < 64) { h1h[tid] = make_uint4(0,0,0,0); h2h[tid] = make_uint4(0,0,0,0); }
  if (tid < HID) h2f[tid] = make_float4(0.f, 0.f, 0.f, 0.f);
  if (tid < BCH) xb[0][tid] = xin[(size_t)(b0 + tid) * T_LEN];
  __syncthreads();

  const uint4* w1p  = wpk + tid;            // Whh1 (m=0), k8 stride = G4
  const uint4* wi2p = wpk + 16 * G4 + tid;  // Wih2 (m=1)
  const uint4* w2p  = wpk + 32 * G4 + tid;  // Whh2 (m=2)

  for (int t = 0; t < T_LEN; ++t) {
    float xpref = 0.f;
    if (((tid & ~3) == 128) && (t + 1) < T_LEN)
      xpref = xin[(size_t)(b0 + (tid & 3)) * T_LEN + t + 1];

    if (tid < 64 && t > 0) store_out(h2f, wo0, wo1, bo, tid, b0, outp, t - 1);

    // ---- phase 1: a1 = Whh1*h1 (+x,bias), a2 = Whh2*h2 (+bias) ----
    float a10 = fmaf(wi1, xb[t & 1][0], bias1);
    float a11 = fmaf(wi1, xb[t & 1][1], bias1);
    float a12 = fmaf(wi1, xb[t & 1][2], bias1);
    float a13 = fmaf(wi1, xb[t & 1][3], bias1);
    float a20 = bias2, a21 = bias2, a22 = bias2, a23 = bias2;
#pragma unroll
    for (int k8 = 0; k8 < 16; ++k8) {
      uint4 W1 = w1p[k8 * G4];
      uint4 W2 = w2p[k8 * G4];
      unsigned int w1a[4] = {W1.x, W1.y, W1.z, W1.w};
      unsigned int w2a[4] = {W2.x, W2.y, W2.z, W2.w};
#pragma unroll
      for (int q = 0; q < 4; ++q) {
        uint4 H1 = h1h[k8 * 4 + q];
        uint4 H2 = h2h[k8 * 4 + q];
        a10 = fdot2(w1a[q], H1.x, a10);
        a11 = fdot2(w1a[q], H1.y, a11);
        a12 = fdot2(w1a[q], H1.z, a12);
        a13 = fdot2(w1a[q], H1.w, a13);
        a20 = fdot2(w2a[q], H2.x, a20);
        a21 = fdot2(w2a[q], H2.y, a21);
        a22 = fdot2(w2a[q], H2.z, a22);
        a23 = fdot2(w2a[q], H2.w, a23);
      }
    }
    float4 A1;
    A1.x = gact(a10, gt); A1.y = gact(a11, gt);
    A1.z = gact(a12, gt); A1.w = gact(a13, gt);
    g1[tid] = A1;
    __syncthreads();

    // ---- phase 2: layer-1 state update (threads 0..127) ----
    if (tid < HID) {
      float4 iv = g1[u], fv = g1[u + HID];
      float4 gv = g1[u + 2 * HID], ov = g1[u + 3 * HID];
      c1.x = fmaf(fv.x, c1.x, iv.x * gv.x);
      c1.y = fmaf(fv.y, c1.y, iv.y * gv.y);
      c1.z = fmaf(fv.z, c1.z, iv.z * gv.z);
      c1.w = fmaf(fv.w, c1.w, iv.w * gv.w);
      float4 hv;
      hv.x = ov.x * ftanh(c1.x);
      hv.y = ov.y * ftanh(c1.y);
      hv.z = ov.z * ftanh(c1.z);
      hv.w = ov.w * ftanh(c1.w);
      _Float16* hp = (_Float16*)h1h;
      int hb = (u >> 1) * 8 + (u & 1);   // half index: (k2*4+b)*2 + parity
      hp[hb + 0] = (_Float16)hv.x;
      hp[hb + 2] = (_Float16)hv.y;
      hp[hb + 4] = (_Float16)hv.z;
      hp[hb + 6] = (_Float16)hv.w;
    }
    __syncthreads();

    // ---- phase 3: a2 += Wih2 * h1(t) ----
#pragma unroll
    for (int k8 = 0; k8 < 16; ++k8) {
      uint4 Wi = wi2p[k8 * G4];
      unsigned int wia[4] = {Wi.x, Wi.y, Wi.z, Wi.w};
#pragma unroll
      for (int q = 0; q < 4; ++q) {
        uint4 H1 = h1h[k8 * 4 + q];
        a20 = fdot2(wia[q], H1.x, a20);
        a21 = fdot2(wia[q], H1.y, a21);
        a22 = fdot2(wia[q], H1.z, a22);
        a23 = fdot2(wia[q], H1.w, a23);
      }
    }
    float4 A2;
    A2.x = gact(a20, gt); A2.y = gact(a21, gt);
    A2.z = gact(a22, gt); A2.w = gact(a23, gt);
    g2[tid] = A2;
    __syncthreads();

    // ---- phase 4: layer-2 state update; commit x prefetch ----
    if (tid < HID) {
      float4 iv = g2[u], fv = g2[u + HID];
      float4 gv = g2[u + 2 * HID], ov = g2[u + 3 * HID];
      c2.x = fmaf(fv.x, c2.x, iv.x * gv.x);
      c2.y = fmaf(fv.y, c2.y, iv.y * gv.y);
      c2.z = fmaf(fv.z, c2.z, iv.z * gv.z);
      c2.w = fmaf(fv.w, c2.w, iv.w * gv.w);
      float4 hv;
      hv.x = ov.x * ftanh(c2.x);
      hv.y = ov.y * ftanh(c2.y);
      hv.z = ov.z * ftanh(c2.z);
      hv.w = ov.w * ftanh(c2.w);
      h2f[u] = hv;
      _Float16* hp = (_Float16*)h2h;
      int hb = (u >> 1) * 8 + (u & 1);
      hp[hb + 0] = (_Float16)hv.x;
      hp[hb + 2] = (_Float16)hv.y;
      hp[hb + 4] = (_Float16)hv.z;
      hp[hb + 6] = (_Float16)hv.w;
    } else if (((tid & ~3) == 128) && (t + 1) < T_LEN) {
      xb[(t + 1) & 1][tid & 3] = xpref;
    }
    __syncthreads();
  }
  if (tid < 64) store_out(h2f, wo0, wo1, bo, tid, b0, outp, T_LEN - 1);
}

// ---------------------------------------------------------------------------
// Fallback (round-1, known-correct fp32 path)
// ---------------------------------------------------------------------------
__global__ void __launch_bounds__(512) transpose_w(
    const float* __restrict__ w1, const float* __restrict__ w2,
    const float* __restrict__ w3, float* __restrict__ o) {
  int m = blockIdx.y;
  const float* src = (m == 0) ? w1 : (m == 1) ? w2 : w3;
  float* dst = o + (size_t)m * G4 * HID;
  int idx = blockIdx.x * 512 + threadIdx.x;
  int j = idx >> 7;
  int k = idx & (HID - 1);
  dst[k * G4 + j] = src[idx];
}

__global__ void __launch_bounds__(512) lstm_fused(
    const float* __restrict__ xin, const float* __restrict__ Wih1,
    const float* __restrict__ bih1, const float* __restrict__ bhh1,
    const float* __restrict__ Whh1, const float* __restrict__ Wih2,
    const float* __restrict__ Whh2, int sk, int sj,
    const float* __restrict__ bih2, const float* __restrict__ bhh2,
    const float* __restrict__ Wout, const float* __restrict__ bout,
    float* __restrict__ outp) {
  __shared__ float4 h1buf[HID];
  __shared__ float4 h2buf[HID];
  __shared__ float4 g1[G4];
  __shared__ float4 g2[G4];
  __shared__ float xb[2][BCH];

  const int tid = threadIdx.x;
  const int b0 = blockIdx.x * BCH;
  const int gt = tid >> 7;

  float bias1 = bih1[tid] + bhh1[tid];
  float bias2 = bih2[tid] + bhh2[tid];
  float wi1 = Wih1[tid];
  float c1_0 = 0.f, c1_1 = 0.f, c1_2 = 0.f, c1_3 = 0.f;
  float c2_0 = 0.f, c2_1 = 0.f, c2_2 = 0.f, c2_3 = 0.f;
  float wo0 = 0.f, wo1 = 0.f, bo = 0.f;
  if (tid < 64) { wo0 = Wout[tid]; wo1 = Wout[tid + 64]; bo = bout[0]; }
  if (tid < HID) {
    h1buf[tid] = make_float4(0.f, 0.f, 0.f, 0.f);
    h2buf[tid] = make_float4(0.f, 0.f, 0.f, 0.f);
  }
  if (tid < BCH) xb[0][tid] = xin[(b0 + tid) * T_LEN];
  __syncthreads();

  const float* wp1  = Whh1 + tid * sj;
  const float* wp2  = Whh2 + tid * sj;
  const float* wpi2 = Wih2 + tid * sj;

  for (int t = 0; t < T_LEN; ++t) {
    float xpref = 0.f;
    if ((tid & ~3) == 128 && (t + 1) < T_LEN)
      xpref = xin[(b0 + (tid & 3)) * T_LEN + t + 1];

    if (tid < 64 && t > 0) store_out(h2buf, wo0, wo1, bo, tid, b0, outp, t - 1);

    float xv0 = xb[t & 1][0], xv1 = xb[t & 1][1];
    float xv2 = xb[t & 1][2], xv3 = xb[t & 1][3];
    float a10 = fmaf(wi1, xv0, bias1);
    float a11 = fmaf(wi1, xv1, bias1);
    float a12 = fmaf(wi1, xv2, bias1);
    float a13 = fmaf(wi1, xv3, bias1);
    float a20 = bias2, a21 = bias2, a22 = bias2, a23 = bias2;
#pragma unroll 8
    for (int k = 0; k < HID; ++k) {
      float w1 = wp1[k * sk];
      float w2 = wp2[k * sk];
      float4 hv1 = h1buf[k];
      float4 hv2 = h2buf[k];
      a10 = fmaf(w1, hv1.x, a10);
      a11 = fmaf(w1, hv1.y, a11);
      a12 = fmaf(w1, hv1.z, a12);
      a13 = fmaf(w1, hv1.w, a13);
      a20 = fmaf(w2, hv2.x, a20);
      a21 = fmaf(w2, hv2.y, a21);
      a22 = fmaf(w2, hv2.z, a22);
      a23 = fmaf(w2, hv2.w, a23);
    }
    float4 A1;
    A1.x = gact(a10, gt); A1.y = gact(a11, gt);
    A1.z = gact(a12, gt); A1.w = gact(a13, gt);
    g1[tid] = A1;
    __syncthreads();

    if (tid < HID) {
      float4 iv = g1[tid], fv = g1[tid + HID];
      float4 gv = g1[tid + 2 * HID], ov = g1[tid + 3 * HID];
      c1_0 = fmaf(fv.x, c1_0, iv.x * gv.x);
      c1_1 = fmaf(fv.y, c1_1, iv.y * gv.y);
      c1_2 = fmaf(fv.z, c1_2, iv.z * gv.z);
      c1_3 = fmaf(fv.w, c1_3, iv.w * gv.w);
      float4 h;
      h.x = ov.x * ftanh(c1_0);
      h.y = ov.y * ftanh(c1_1);
      h.z = ov.z * ftanh(c1_2);
      h.w = ov.w * ftanh(c1_3);
      h1buf[tid] = h;
    }
    __syncthreads();

#pragma unroll 8
    for (int k = 0; k < HID; ++k) {
      float w = wpi2[k * sk];
      float4 hv = h1buf[k];
      a20 = fmaf(w, hv.x, a20);
      a21 = fmaf(w, hv.y, a21);
      a22 = fmaf(w, hv.z, a22);
      a23 = fmaf(w, hv.w, a23);
    }
    float4 A2;
    A2.x = gact(a20, gt); A2.y = gact(a21, gt);
    A2.z = gact(a22, gt); A2.w = gact(a23, gt);
    g2[tid] = A2;
    __syncthreads();

    if (tid < HID) {
      float4 iv = g2[tid], fv = g2[tid + HID];
      float4 gv = g2[tid + 2 * HID], ov = g2[tid + 3 * HID];
      c2_0 = fmaf(fv.x, c2_0, iv.x * gv.x);
      c2_1 = fmaf(fv.y, c2_1, iv.y * gv.y);
      c2_2 = fmaf(fv.z, c2_2, iv.z * gv.z);
      c2_3 = fmaf(fv.w, c2_3, iv.w * gv.w);
      float4 h;
      h.x = ov.x * ftanh(c2_0);
      h.y = ov.y * ftanh(c2_1);
      h.z = ov.z * ftanh(c2_2);
      h.w = ov.w * ftanh(c2_3);
      h2buf[tid] = h;
    } else if ((tid & ~3) == 128 && (t + 1) < T_LEN) {
      xb[(t + 1) & 1][tid & 3] = xpref;
    }
    __syncthreads();
  }
  if (tid < 64) store_out(h2buf, wo0, wo1, bo, tid, b0, outp, T_LEN - 1);
}

extern "C" void kernel_launch(void* const* d_in, const int* in_sizes, int n_in,
                              void* d_out, int out_size, void* d_ws, size_t ws_size,
                              hipStream_t stream) {
  const float* xin  = (const float*)d_in[0];
  const float* Wih1 = (const float*)d_in[1];
  const float* Whh1 = (const float*)d_in[2];
  const float* bih1 = (const float*)d_in[3];
  const float* bhh1 = (const float*)d_in[4];
  const float* Wih2 = (const float*)d_in[5];
  const float* Whh2 = (const float*)d_in[6];
  const float* bih2 = (const float*)d_in[7];
  const float* bhh2 = (const float*)d_in[8];
  const float* Wout = (const float*)d_in[9];
  const float* bout = (const float*)d_in[10];
  float* outp = (float*)d_out;

  const size_t needF16 = (size_t)3 * 16 * G4 * sizeof(uint4);  // 384 KB
  if (ws_size >= needF16) {
    uint4* wpk = (uint4*)d_ws;
    pack_w<<<dim3(32, 3), 256, 0, stream>>>(Whh1, Wih2, Whh2, wpk);
    lstm_f16<<<NG, 512, 0, stream>>>(
        xin, Wih1, bih1, bhh1, wpk, bih2, bhh2, Wout, bout, outp);
    return;
  }

  // fallback: round-1 fp32 kernel
  size_t need = (size_t)3 * G4 * HID * sizeof(float);
  if (ws_size >= need) {
    float* wt = (float*)d_ws;
    transpose_w<<<dim3(128, 3), 512, 0, stream>>>(Whh1, Wih2, Whh2, wt);
    lstm_fused<<<NG, 512, 0, stream>>>(
        xin, Wih1, bih1, bhh1,
        wt, wt + (size_t)G4 * HID, wt + (size_t)2 * G4 * HID, G4, 1,
        bih2, bhh2, Wout, bout, outp);
  } else {
    lstm_fused<<<NG, 512, 0, stream>>>(
        xin, Wih1, bih1, bhh1,
        Whh1, Wih2, Whh2, 1, HID,
        bih2, bhh2, Wout, bout, outp);
  }
}

// Round 4
// 39141.217 us; speedup vs baseline: 3.9467x; 3.9467x over previous
//
#include <hip/hip_runtime.h>

#define T_LEN 1024
#define HID   128
#define G4    512
#define NW2   256     // WGs for the register-resident path (BCH=2)
#define NG    128     // fallback WGs (BCH=4)
#define BCH   4

typedef _Float16 h2_t __attribute__((ext_vector_type(2)));

__device__ __forceinline__ h2_t as_h2(unsigned int u) {
  union { unsigned int u; h2_t h; } c; c.u = u; return c.h;
}
__device__ __forceinline__ float fdot2(unsigned int a, unsigned int b, float c) {
  return __builtin_amdgcn_fdot2(as_h2(a), as_h2(b), c, false);
}

__device__ __forceinline__ float fsig(float v) {
  return __builtin_amdgcn_rcpf(1.0f + __expf(-v));
}
__device__ __forceinline__ float ftanh(float v) {
  float a = fabsf(v);
  float e = __expf(-2.0f * a);
  float t = (1.0f - e) * __builtin_amdgcn_rcpf(1.0f + e);
  return copysignf(t, v);
}
__device__ __forceinline__ float gact(float v, int gt) {
  return (gt == 2) ? ftanh(v) : fsig(v);
}

// ---------------------------------------------------------------------------
// Pack fp32 [512][128] weights -> per-row half2 stream:
// dst[m*32768 + j*64 + k2] = half2(w[j][2k2], w[j][2k2+1])
// m: 0=Whh1, 1=Wih2, 2=Whh2. Row j's 64 uints are contiguous (256 B).
// ---------------------------------------------------------------------------
__global__ void __launch_bounds__(256) pack_w2(
    const float* __restrict__ wa, const float* __restrict__ wb,
    const float* __restrict__ wc, unsigned int* __restrict__ dst) {
  int idx = blockIdx.x * 256 + threadIdx.x;      // 0 .. 98303
  int m   = idx >> 15;
  int r   = idx & 32767;
  int j   = r >> 6;
  int k2  = r & 63;
  const float* src = (m == 0) ? wa : (m == 1) ? wb : wc;
  float2 v = *reinterpret_cast<const float2*>(src + (size_t)j * HID + 2 * k2);
  h2_t h;
  h.x = (_Float16)v.x;
  h.y = (_Float16)v.y;
  dst[idx] = __builtin_bit_cast(unsigned int, h);
}

__device__ __forceinline__ void store_out2(const float2* h2f, float wo0, float wo1,
                                           float bo, int tid, int b0,
                                           float* __restrict__ outp, int t) {
  // wave 0 only (tid < 64); lane covers units tid and tid+64
  float2 ha = h2f[tid];
  float2 hb = h2f[tid + 64];
  float p0 = wo0 * ha.x + wo1 * hb.x;
  float p1 = wo0 * ha.y + wo1 * hb.y;
#pragma unroll
  for (int off = 1; off < 64; off <<= 1) {
    p0 += __shfl_xor(p0, off, 64);
    p1 += __shfl_xor(p1, off, 64);
  }
  if (tid < 2) {
    float v = (tid == 0) ? p0 : p1;
    outp[(size_t)(b0 + tid) * T_LEN + t] = v + bo;
  }
}

// ---------------------------------------------------------------------------
// Register-resident fp16 weights. 256 WGs x 512 threads; WG owns 2 batches.
// Thread tid owns gate row tid for both layers; its 3x128 fp16 weights live
// in 192 VGPRs (constant-indexed arrays, fully unrolled loops). h1/h2 in LDS
// as half2, layout [k4] = uint4{b0k01, b0k23, b1k01, b1k23} -> every k-loop
// iteration is ONE broadcast ds_read_b128 per matrix. No global memory in
// the steady-state loop.
// ---------------------------------------------------------------------------
__global__ void __launch_bounds__(512, 1) lstm_reg(
    const float* __restrict__ xin, const float* __restrict__ Wih1,
    const float* __restrict__ bih1, const float* __restrict__ bhh1,
    const unsigned int* __restrict__ wpk,
    const float* __restrict__ bih2, const float* __restrict__ bhh2,
    const float* __restrict__ Wout, const float* __restrict__ bout,
    float* __restrict__ outp)
{
  __shared__ uint4  h1h[32];      // [k4] {b0k01,b0k23,b1k01,b1k23}
  __shared__ uint4  h2h[32];
  __shared__ float2 g1[G4];       // activated gates, fp32, 2 batches
  __shared__ float2 g2[G4];
  __shared__ float2 h2f[HID];     // fp32 h2 for output dot
  __shared__ float  xb[2][2];

  const int tid = threadIdx.x;
  const int b0  = blockIdx.x * 2;
  const int gt  = tid >> 7;
  const int u   = tid & (HID - 1);

  // ---- one-time: weights into registers ----
  unsigned int wr1[64], wri[64], wr2[64];
  {
    const uint4* p1 = reinterpret_cast<const uint4*>(wpk + (size_t)tid * 64);
    const uint4* pi = reinterpret_cast<const uint4*>(wpk + 32768 + (size_t)tid * 64);
    const uint4* p2 = reinterpret_cast<const uint4*>(wpk + 65536 + (size_t)tid * 64);
#pragma unroll
    for (int i = 0; i < 16; ++i) {
      uint4 a = p1[i];
      wr1[4*i] = a.x; wr1[4*i+1] = a.y; wr1[4*i+2] = a.z; wr1[4*i+3] = a.w;
      uint4 b = pi[i];
      wri[4*i] = b.x; wri[4*i+1] = b.y; wri[4*i+2] = b.z; wri[4*i+3] = b.w;
      uint4 c = p2[i];
      wr2[4*i] = c.x; wr2[4*i+1] = c.y; wr2[4*i+2] = c.z; wr2[4*i+3] = c.w;
    }
  }
  const float bias1 = bih1[tid] + bhh1[tid];
  const float bias2 = bih2[tid] + bhh2[tid];
  const float wi1   = Wih1[tid];
  float wo0 = 0.f, wo1 = 0.f, bo = 0.f;
  if (tid < 64) { wo0 = Wout[tid]; wo1 = Wout[tid + 64]; bo = bout[0]; }
  float c1x = 0.f, c1y = 0.f, c2x = 0.f, c2y = 0.f;

  if (tid < 32) { h1h[tid] = make_uint4(0,0,0,0); h2h[tid] = make_uint4(0,0,0,0); }
  if (tid < HID) h2f[tid] = make_float2(0.f, 0.f);
  if (tid < 2)  xb[0][tid] = xin[(size_t)(b0 + tid) * T_LEN];
  __syncthreads();

  for (int t = 0; t < T_LEN; ++t) {
    float xpref = 0.f;
    if (((tid & ~1) == 128) && (t + 1) < T_LEN)
      xpref = xin[(size_t)(b0 + (tid & 1)) * T_LEN + t + 1];

    if (tid < 64 && t > 0) store_out2(h2f, wo0, wo1, bo, tid, b0, outp, t - 1);

    // ---- phase 1: a1 = Whh1*h1 (+x,bias);  a2 = Whh2*h2 (+bias) ----
    float a10 = fmaf(wi1, xb[t & 1][0], bias1);
    float a11 = fmaf(wi1, xb[t & 1][1], bias1);
    float a20 = bias2, a21 = bias2;
#pragma unroll
    for (int i = 0; i < 32; ++i) {
      uint4 H1 = h1h[i];
      uint4 H2 = h2h[i];
      a10 = fdot2(wr1[2*i],   H1.x, a10);
      a10 = fdot2(wr1[2*i+1], H1.y, a10);
      a11 = fdot2(wr1[2*i],   H1.z, a11);
      a11 = fdot2(wr1[2*i+1], H1.w, a11);
      a20 = fdot2(wr2[2*i],   H2.x, a20);
      a20 = fdot2(wr2[2*i+1], H2.y, a20);
      a21 = fdot2(wr2[2*i],   H2.z, a21);
      a21 = fdot2(wr2[2*i+1], H2.w, a21);
    }
    g1[tid] = make_float2(gact(a10, gt), gact(a11, gt));
    __syncthreads();

    // ---- phase 2: layer-1 state update (threads 0..127) ----
    if (tid < HID) {
      float2 iv = g1[u], fv = g1[u + HID];
      float2 gv = g1[u + 2 * HID], ov = g1[u + 3 * HID];
      c1x = fmaf(fv.x, c1x, iv.x * gv.x);
      c1y = fmaf(fv.y, c1y, iv.y * gv.y);
      float hx = ov.x * ftanh(c1x);
      float hy = ov.y * ftanh(c1y);
      _Float16* hp = (_Float16*)h1h;
      int base = (u >> 2) * 8 + (u & 3);   // halves: [k4][b*4 + k&3]
      hp[base]     = (_Float16)hx;
      hp[base + 4] = (_Float16)hy;
    }
    __syncthreads();

    // ---- phase 3: a2 += Wih2 * h1(t) ----
#pragma unroll
    for (int i = 0; i < 32; ++i) {
      uint4 H1 = h1h[i];
      a20 = fdot2(wri[2*i],   H1.x, a20);
      a20 = fdot2(wri[2*i+1], H1.y, a20);
      a21 = fdot2(wri[2*i],   H1.z, a21);
      a21 = fdot2(wri[2*i+1], H1.w, a21);
    }
    g2[tid] = make_float2(gact(a20, gt), gact(a21, gt));
    __syncthreads();

    // ---- phase 4: layer-2 state update; commit x prefetch ----
    if (tid < HID) {
      float2 iv = g2[u], fv = g2[u + HID];
      float2 gv = g2[u + 2 * HID], ov = g2[u + 3 * HID];
      c2x = fmaf(fv.x, c2x, iv.x * gv.x);
      c2y = fmaf(fv.y, c2y, iv.y * gv.y);
      float hx = ov.x * ftanh(c2x);
      float hy = ov.y * ftanh(c2y);
      h2f[u] = make_float2(hx, hy);
      _Float16* hp = (_Float16*)h2h;
      int base = (u >> 2) * 8 + (u & 3);
      hp[base]     = (_Float16)hx;
      hp[base + 4] = (_Float16)hy;
    } else if (((tid & ~1) == 128) && (t + 1) < T_LEN) {
      xb[(t + 1) & 1][tid & 1] = xpref;
    }
    __syncthreads();
  }
  if (tid < 64) store_out2(h2f, wo0, wo1, bo, tid, b0, outp, T_LEN - 1);
}

// ---------------------------------------------------------------------------
// Fallback (round-1, known-correct fp32 path)
// ---------------------------------------------------------------------------
__global__ void __launch_bounds__(512) transpose_w(
    const float* __restrict__ w1, const float* __restrict__ w2,
    const float* __restrict__ w3, float* __restrict__ o) {
  int m = blockIdx.y;
  const float* src = (m == 0) ? w1 : (m == 1) ? w2 : w3;
  float* dst = o + (size_t)m * G4 * HID;
  int idx = blockIdx.x * 512 + threadIdx.x;
  int j = idx >> 7;
  int k = idx & (HID - 1);
  dst[k * G4 + j] = src[idx];
}

__device__ __forceinline__ void store_out4(const float4* h2buf, float wo0, float wo1,
                                           float bo, int tid, int b0,
                                           float* __restrict__ outp, int t) {
  float4 ha = h2buf[tid];
  float4 hb = h2buf[tid + 64];
  float p0 = wo0 * ha.x + wo1 * hb.x;
  float p1 = wo0 * ha.y + wo1 * hb.y;
  float p2 = wo0 * ha.z + wo1 * hb.z;
  float p3 = wo0 * ha.w + wo1 * hb.w;
#pragma unroll
  for (int off = 1; off < 64; off <<= 1) {
    p0 += __shfl_xor(p0, off, 64);
    p1 += __shfl_xor(p1, off, 64);
    p2 += __shfl_xor(p2, off, 64);
    p3 += __shfl_xor(p3, off, 64);
  }
  if (tid < BCH) {
    float v = (tid == 0) ? p0 : (tid == 1) ? p1 : (tid == 2) ? p2 : p3;
    outp[(size_t)(b0 + tid) * T_LEN + t] = v + bo;
  }
}

__global__ void __launch_bounds__(512) lstm_fused(
    const float* __restrict__ xin, const float* __restrict__ Wih1,
    const float* __restrict__ bih1, const float* __restrict__ bhh1,
    const float* __restrict__ Whh1, const float* __restrict__ Wih2,
    const float* __restrict__ Whh2, int sk, int sj,
    const float* __restrict__ bih2, const float* __restrict__ bhh2,
    const float* __restrict__ Wout, const float* __restrict__ bout,
    float* __restrict__ outp) {
  __shared__ float4 h1buf[HID];
  __shared__ float4 h2buf[HID];
  __shared__ float4 g1[G4];
  __shared__ float4 g2[G4];
  __shared__ float xb[2][BCH];

  const int tid = threadIdx.x;
  const int b0 = blockIdx.x * BCH;
  const int gt = tid >> 7;

  float bias1 = bih1[tid] + bhh1[tid];
  float bias2 = bih2[tid] + bhh2[tid];
  float wi1 = Wih1[tid];
  float c1_0 = 0.f, c1_1 = 0.f, c1_2 = 0.f, c1_3 = 0.f;
  float c2_0 = 0.f, c2_1 = 0.f, c2_2 = 0.f, c2_3 = 0.f;
  float wo0 = 0.f, wo1 = 0.f, bo = 0.f;
  if (tid < 64) { wo0 = Wout[tid]; wo1 = Wout[tid + 64]; bo = bout[0]; }
  if (tid < HID) {
    h1buf[tid] = make_float4(0.f, 0.f, 0.f, 0.f);
    h2buf[tid] = make_float4(0.f, 0.f, 0.f, 0.f);
  }
  if (tid < BCH) xb[0][tid] = xin[(b0 + tid) * T_LEN];
  __syncthreads();

  const float* wp1  = Whh1 + tid * sj;
  const float* wp2  = Whh2 + tid * sj;
  const float* wpi2 = Wih2 + tid * sj;

  for (int t = 0; t < T_LEN; ++t) {
    float xpref = 0.f;
    if ((tid & ~3) == 128 && (t + 1) < T_LEN)
      xpref = xin[(b0 + (tid & 3)) * T_LEN + t + 1];

    if (tid < 64 && t > 0) store_out4(h2buf, wo0, wo1, bo, tid, b0, outp, t - 1);

    float xv0 = xb[t & 1][0], xv1 = xb[t & 1][1];
    float xv2 = xb[t & 1][2], xv3 = xb[t & 1][3];
    float a10 = fmaf(wi1, xv0, bias1);
    float a11 = fmaf(wi1, xv1, bias1);
    float a12 = fmaf(wi1, xv2, bias1);
    float a13 = fmaf(wi1, xv3, bias1);
    float a20 = bias2, a21 = bias2, a22 = bias2, a23 = bias2;
#pragma unroll 8
    for (int k = 0; k < HID; ++k) {
      float w1 = wp1[k * sk];
      float w2 = wp2[k * sk];
      float4 hv1 = h1buf[k];
      float4 hv2 = h2buf[k];
      a10 = fmaf(w1, hv1.x, a10);
      a11 = fmaf(w1, hv1.y, a11);
      a12 = fmaf(w1, hv1.z, a12);
      a13 = fmaf(w1, hv1.w, a13);
      a20 = fmaf(w2, hv2.x, a20);
      a21 = fmaf(w2, hv2.y, a21);
      a22 = fmaf(w2, hv2.z, a22);
      a23 = fmaf(w2, hv2.w, a23);
    }
    float4 A1;
    A1.x = gact(a10, gt); A1.y = gact(a11, gt);
    A1.z = gact(a12, gt); A1.w = gact(a13, gt);
    g1[tid] = A1;
    __syncthreads();

    if (tid < HID) {
      float4 iv = g1[tid], fv = g1[tid + HID];
      float4 gv = g1[tid + 2 * HID], ov = g1[tid + 3 * HID];
      c1_0 = fmaf(fv.x, c1_0, iv.x * gv.x);
      c1_1 = fmaf(fv.y, c1_1, iv.y * gv.y);
      c1_2 = fmaf(fv.z, c1_2, iv.z * gv.z);
      c1_3 = fmaf(fv.w, c1_3, iv.w * gv.w);
      float4 h;
      h.x = ov.x * ftanh(c1_0);
      h.y = ov.y * ftanh(c1_1);
      h.z = ov.z * ftanh(c1_2);
      h.w = ov.w * ftanh(c1_3);
      h1buf[tid] = h;
    }
    __syncthreads();

#pragma unroll 8
    for (int k = 0; k < HID; ++k) {
      float w = wpi2[k * sk];
      float4 hv = h1buf[k];
      a20 = fmaf(w, hv.x, a20);
      a21 = fmaf(w, hv.y, a21);
      a22 = fmaf(w, hv.z, a22);
      a23 = fmaf(w, hv.w, a23);
    }
    float4 A2;
    A2.x = gact(a20, gt); A2.y = gact(a21, gt);
    A2.z = gact(a22, gt); A2.w = gact(a23, gt);
    g2[tid] = A2;
    __syncthreads();

    if (tid < HID) {
      float4 iv = g2[tid], fv = g2[tid + HID];
      float4 gv = g2[tid + 2 * HID], ov = g2[tid + 3 * HID];
      c2_0 = fmaf(fv.x, c2_0, iv.x * gv.x);
      c2_1 = fmaf(fv.y, c2_1, iv.y * gv.y);
      c2_2 = fmaf(fv.z, c2_2, iv.z * gv.z);
      c2_3 = fmaf(fv.w, c2_3, iv.w * gv.w);
      float4 h;
      h.x = ov.x * ftanh(c2_0);
      h.y = ov.y * ftanh(c2_1);
      h.z = ov.z * ftanh(c2_2);
      h.w = ov.w * ftanh(c2_3);
      h2buf[tid] = h;
    } else if ((tid & ~3) == 128 && (t + 1) < T_LEN) {
      xb[(t + 1) & 1][tid & 3] = xpref;
    }
    __syncthreads();
  }
  if (tid < 64) store_out4(h2buf, wo0, wo1, bo, tid, b0, outp, T_LEN - 1);
}

extern "C" void kernel_launch(void* const* d_in, const int* in_sizes, int n_in,
                              void* d_out, int out_size, void* d_ws, size_t ws_size,
                              hipStream_t stream) {
  const float* xin  = (const float*)d_in[0];
  const float* Wih1 = (const float*)d_in[1];
  const float* Whh1 = (const float*)d_in[2];
  const float* bih1 = (const float*)d_in[3];
  const float* bhh1 = (const float*)d_in[4];
  const float* Wih2 = (const float*)d_in[5];
  const float* Whh2 = (const float*)d_in[6];
  const float* bih2 = (const float*)d_in[7];
  const float* bhh2 = (const float*)d_in[8];
  const float* Wout = (const float*)d_in[9];
  const float* bout = (const float*)d_in[10];
  float* outp = (float*)d_out;

  const size_t needPk = (size_t)3 * G4 * 64 * sizeof(unsigned int);  // 384 KB
  if (ws_size >= needPk) {
    unsigned int* wpk = (unsigned int*)d_ws;
    pack_w2<<<384, 256, 0, stream>>>(Whh1, Wih2, Whh2, wpk);
    lstm_reg<<<NW2, 512, 0, stream>>>(
        xin, Wih1, bih1, bhh1, wpk, bih2, bhh2, Wout, bout, outp);
    return;
  }

  // fallback: round-1 fp32 kernel
  size_t need = (size_t)3 * G4 * HID * sizeof(float);
  if (ws_size >= need) {
    float* wt = (float*)d_ws;
    transpose_w<<<dim3(128, 3), 512, 0, stream>>>(Whh1, Wih2, Whh2, wt);
    lstm_fused<<<NG, 512, 0, stream>>>(
        xin, Wih1, bih1, bhh1,
        wt, wt + (size_t)G4 * HID, wt + (size_t)2 * G4 * HID, G4, 1,
        bih2, bhh2, Wout, bout, outp);
  } else {
    lstm_fused<<<NG, 512, 0, stream>>>(
        xin, Wih1, bih1, bhh1,
        Whh1, Wih2, Whh2, 1, HID,
        bih2, bhh2, Wout, bout, outp);
  }
}

// Round 5
// 3001.045 us; speedup vs baseline: 51.4744x; 13.0425x over previous
//
#include <hip/hip_runtime.h>

#define T_LEN 1024
#define HID   128
#define G4    512
#define BCH   4
#define NG    128

typedef _Float16 h2_t  __attribute__((ext_vector_type(2)));
typedef _Float16 f16x8 __attribute__((ext_vector_type(8)));
typedef float    f32x4n __attribute__((ext_vector_type(4)));

#define HB_STR 136   // padded halves per batch-row of hB (bank-balanced)

__device__ __forceinline__ float fsig(float v) {
  return __builtin_amdgcn_rcpf(1.0f + __expf(-v));
}
__device__ __forceinline__ float ftanh(float v) {
  float a = fabsf(v);
  float e = __expf(-2.0f * a);
  float t = (1.0f - e) * __builtin_amdgcn_rcpf(1.0f + e);
  return copysignf(t, v);
}
__device__ __forceinline__ float gact(float v, int gt) {
  return (gt == 2) ? ftanh(v) : fsig(v);
}

// ---------------------------------------------------------------------------
// Pack fp32 weights into MFMA A-fragments (fp16).
// dst[((m*8 + w)*16 + f)*64 + l] = uint4 {8 halves} where
//   row = 64w + 16*(f>>2) + (l&15),  k0 = 32*(f&3) + (l>>4)*8
// m: 0=Whh1, 1=Whh2, 2=Wih2.  Total 3*8*16*64 = 24576 uint4 = 384 KB.
// ---------------------------------------------------------------------------
__global__ void __launch_bounds__(256) pack_frag(
    const float* __restrict__ wa, const float* __restrict__ wb,
    const float* __restrict__ wc, uint4* __restrict__ dst) {
  int idx = blockIdx.x * 256 + threadIdx.x;   // 0..24575
  int l = idx & 63;
  int f = (idx >> 6) & 15;
  int w = (idx >> 10) & 7;
  int m = idx >> 13;
  const float* src = (m == 0) ? wa : (m == 1) ? wb : wc;
  int row = 64 * w + 16 * (f >> 2) + (l & 15);
  int k0  = 32 * (f & 3) + (l >> 4) * 8;
  const float* s = src + (size_t)row * HID + k0;
  unsigned int r[4];
#pragma unroll
  for (int q = 0; q < 4; ++q) {
    h2_t h;
    h.x = (_Float16)s[2 * q];
    h.y = (_Float16)s[2 * q + 1];
    r[q] = __builtin_bit_cast(unsigned int, h);
  }
  dst[idx] = make_uint4(r[0], r[1], r[2], r[3]);
}

__device__ __forceinline__ void store_out4(const float4* h2buf, float wo0, float wo1,
                                           float bo, int tid, int b0,
                                           float* __restrict__ outp, int t) {
  float4 ha = h2buf[tid];
  float4 hb = h2buf[tid + 64];
  float p0 = wo0 * ha.x + wo1 * hb.x;
  float p1 = wo0 * ha.y + wo1 * hb.y;
  float p2 = wo0 * ha.z + wo1 * hb.z;
  float p3 = wo0 * ha.w + wo1 * hb.w;
#pragma unroll
  for (int off = 1; off < 64; off <<= 1) {
    p0 += __shfl_xor(p0, off, 64);
    p1 += __shfl_xor(p1, off, 64);
    p2 += __shfl_xor(p2, off, 64);
    p3 += __shfl_xor(p3, off, 64);
  }
  if (tid < BCH) {
    float v = (tid == 0) ? p0 : (tid == 1) ? p1 : (tid == 2) ? p2 : p3;
    outp[(size_t)(b0 + tid) * T_LEN + t] = v + bo;
  }
}

// ---------------------------------------------------------------------------
// MFMA kernel: 128 WGs x 512 threads, 4 batches/WG. Wave w owns gate rows
// [64w, 64w+64) of all three matrices as register-resident fp16 A-fragments
// (48 frags = 192 VGPRs, asm-laundered so they can't be rematerialized).
// h1/h2 live in LDS as fp16 [16 cols][136] (B-fragment layout, cols 4..15
// stay zero). Gate raw/act + c-state in LDS fp32.
// ---------------------------------------------------------------------------
__global__ void __launch_bounds__(512, 2) lstm_mfma(
    const float* __restrict__ xin, const float* __restrict__ Wih1,
    const float* __restrict__ bih1, const float* __restrict__ bhh1,
    const uint4* __restrict__ wfrag,
    const float* __restrict__ bih2, const float* __restrict__ bhh2,
    const float* __restrict__ Wout, const float* __restrict__ bout,
    float* __restrict__ outp)
{
  __shared__ _Float16 hB1[16 * HB_STR];
  __shared__ _Float16 hB2[16 * HB_STR];
  __shared__ float4   g1b[G4];      // raw, then (in-place) activated gates1
  __shared__ float4   g2b[G4];
  __shared__ float4   c1s[HID], c2s[HID];
  __shared__ float4   h2f[HID];     // fp32 h2 for the output dot
  __shared__ float    xb[2][BCH];

  const int tid = threadIdx.x;
  const int l   = tid & 63;
  const int w   = tid >> 6;
  const int b0  = blockIdx.x * BCH;
  const int gt  = tid >> 7;
  const int col = l & 15;

  // ---- one-time: A-fragments into registers ----
  f32x4n A1f[16], A2f[16], AIf[16];
#pragma unroll
  for (int f = 0; f < 16; ++f) {
    A1f[f] = __builtin_bit_cast(f32x4n, wfrag[((0 * 8 + w) * 16 + f) * 64 + l]);
    A2f[f] = __builtin_bit_cast(f32x4n, wfrag[((1 * 8 + w) * 16 + f) * 64 + l]);
    AIf[f] = __builtin_bit_cast(f32x4n, wfrag[((2 * 8 + w) * 16 + f) * 64 + l]);
  }
#pragma unroll
  for (int f = 0; f < 16; ++f)
    asm volatile("" : "+v"(A1f[f]), "+v"(A2f[f]), "+v"(AIf[f]));

  const float bias1 = bih1[tid] + bhh1[tid];
  const float bias2 = bih2[tid] + bhh2[tid];
  const float wi1   = Wih1[tid];
  float wo0 = 0.f, wo1 = 0.f, bo = 0.f;
  if (tid < 64) { wo0 = Wout[tid]; wo1 = Wout[tid + 64]; bo = bout[0]; }

  // ---- zero-init LDS ----
  {
    unsigned int* z1 = (unsigned int*)hB1;
    unsigned int* z2 = (unsigned int*)hB2;
    for (int i = tid; i < 16 * HB_STR / 2; i += 512) { z1[i] = 0u; z2[i] = 0u; }
    if (tid < HID) {
      c1s[tid] = make_float4(0.f, 0.f, 0.f, 0.f);
      c2s[tid] = make_float4(0.f, 0.f, 0.f, 0.f);
      h2f[tid] = make_float4(0.f, 0.f, 0.f, 0.f);
    }
    if (tid < BCH) xb[0][tid] = xin[(size_t)(b0 + tid) * T_LEN];
  }
  __syncthreads();

  const _Float16* hb1p = &hB1[(size_t)(l & 15) * HB_STR + (l >> 4) * 8];
  const _Float16* hb2p = &hB2[(size_t)(l & 15) * HB_STR + (l >> 4) * 8];

  for (int t = 0; t < T_LEN; ++t) {
    float xpref = 0.f;
    if (((tid & ~3) == 128) && (t + 1) < T_LEN)
      xpref = xin[(size_t)(b0 + (tid & 3)) * T_LEN + t + 1];

    if (tid < 64 && t > 0) store_out4(h2f, wo0, wo1, bo, tid, b0, outp, t - 1);

    // ---- P1: MFMA  a1 = Whh1*h1, a2 = Whh2*h2 (accumulated in C regs) ----
    f32x4n C10 = {0,0,0,0}, C11 = {0,0,0,0}, C12 = {0,0,0,0}, C13 = {0,0,0,0};
    f32x4n C20 = {0,0,0,0}, C21 = {0,0,0,0}, C22 = {0,0,0,0}, C23 = {0,0,0,0};
#pragma unroll
    for (int kt = 0; kt < 4; ++kt) {
      f16x8 b1 = *reinterpret_cast<const f16x8*>(hb1p + kt * 32);
      f16x8 b2 = *reinterpret_cast<const f16x8*>(hb2p + kt * 32);
      C10 = __builtin_amdgcn_mfma_f32_16x16x32_f16(__builtin_bit_cast(f16x8, A1f[0*4+kt]), b1, C10, 0, 0, 0);
      C11 = __builtin_amdgcn_mfma_f32_16x16x32_f16(__builtin_bit_cast(f16x8, A1f[1*4+kt]), b1, C11, 0, 0, 0);
      C12 = __builtin_amdgcn_mfma_f32_16x16x32_f16(__builtin_bit_cast(f16x8, A1f[2*4+kt]), b1, C12, 0, 0, 0);
      C13 = __builtin_amdgcn_mfma_f32_16x16x32_f16(__builtin_bit_cast(f16x8, A1f[3*4+kt]), b1, C13, 0, 0, 0);
      C20 = __builtin_amdgcn_mfma_f32_16x16x32_f16(__builtin_bit_cast(f16x8, A2f[0*4+kt]), b2, C20, 0, 0, 0);
      C21 = __builtin_amdgcn_mfma_f32_16x16x32_f16(__builtin_bit_cast(f16x8, A2f[1*4+kt]), b2, C21, 0, 0, 0);
      C22 = __builtin_amdgcn_mfma_f32_16x16x32_f16(__builtin_bit_cast(f16x8, A2f[2*4+kt]), b2, C22, 0, 0, 0);
      C23 = __builtin_amdgcn_mfma_f32_16x16x32_f16(__builtin_bit_cast(f16x8, A2f[3*4+kt]), b2, C23, 0, 0, 0);
    }
    if (col < 4) {
      int rb = (l >> 4) * 4;
#pragma unroll
      for (int r = 0; r < 4; ++r) {
        ((float*)&g1b[64 * w + 16 * 0 + rb + r])[col] = C10[r];
        ((float*)&g1b[64 * w + 16 * 1 + rb + r])[col] = C11[r];
        ((float*)&g1b[64 * w + 16 * 2 + rb + r])[col] = C12[r];
        ((float*)&g1b[64 * w + 16 * 3 + rb + r])[col] = C13[r];
      }
    }
    __syncthreads();

    // ---- P2: activate gates1 (all 512 threads, row tid) ----
    {
      float4 rv = g1b[tid];
      float xv0 = xb[t & 1][0], xv1 = xb[t & 1][1];
      float xv2 = xb[t & 1][2], xv3 = xb[t & 1][3];
      float4 av;
      av.x = gact(rv.x + fmaf(wi1, xv0, bias1), gt);
      av.y = gact(rv.y + fmaf(wi1, xv1, bias1), gt);
      av.z = gact(rv.z + fmaf(wi1, xv2, bias1), gt);
      av.w = gact(rv.w + fmaf(wi1, xv3, bias1), gt);
      g1b[tid] = av;
    }
    __syncthreads();

    // ---- P3: layer-1 state update (threads 0..127) ----
    if (tid < HID) {
      float4 iv = g1b[tid], fv = g1b[tid + HID];
      float4 gv = g1b[tid + 2 * HID], ov = g1b[tid + 3 * HID];
      float4 c = c1s[tid];
      c.x = fmaf(fv.x, c.x, iv.x * gv.x);
      c.y = fmaf(fv.y, c.y, iv.y * gv.y);
      c.z = fmaf(fv.z, c.z, iv.z * gv.z);
      c.w = fmaf(fv.w, c.w, iv.w * gv.w);
      c1s[tid] = c;
      hB1[0 * HB_STR + tid] = (_Float16)(ov.x * ftanh(c.x));
      hB1[1 * HB_STR + tid] = (_Float16)(ov.y * ftanh(c.y));
      hB1[2 * HB_STR + tid] = (_Float16)(ov.z * ftanh(c.z));
      hB1[3 * HB_STR + tid] = (_Float16)(ov.w * ftanh(c.w));
    }
    __syncthreads();

    // ---- P4: MFMA  a2 += Wih2 * h1(t) ----
#pragma unroll
    for (int kt = 0; kt < 4; ++kt) {
      f16x8 b1 = *reinterpret_cast<const f16x8*>(hb1p + kt * 32);
      C20 = __builtin_amdgcn_mfma_f32_16x16x32_f16(__builtin_bit_cast(f16x8, AIf[0*4+kt]), b1, C20, 0, 0, 0);
      C21 = __builtin_amdgcn_mfma_f32_16x16x32_f16(__builtin_bit_cast(f16x8, AIf[1*4+kt]), b1, C21, 0, 0, 0);
      C22 = __builtin_amdgcn_mfma_f32_16x16x32_f16(__builtin_bit_cast(f16x8, AIf[2*4+kt]), b1, C22, 0, 0, 0);
      C23 = __builtin_amdgcn_mfma_f32_16x16x32_f16(__builtin_bit_cast(f16x8, AIf[3*4+kt]), b1, C23, 0, 0, 0);
    }
    if (col < 4) {
      int rb = (l >> 4) * 4;
#pragma unroll
      for (int r = 0; r < 4; ++r) {
        ((float*)&g2b[64 * w + 16 * 0 + rb + r])[col] = C20[r];
        ((float*)&g2b[64 * w + 16 * 1 + rb + r])[col] = C21[r];
        ((float*)&g2b[64 * w + 16 * 2 + rb + r])[col] = C22[r];
        ((float*)&g2b[64 * w + 16 * 3 + rb + r])[col] = C23[r];
      }
    }
    __syncthreads();

    // ---- P5: activate gates2 ----
    {
      float4 rv = g2b[tid];
      float4 av;
      av.x = gact(rv.x + bias2, gt);
      av.y = gact(rv.y + bias2, gt);
      av.z = gact(rv.z + bias2, gt);
      av.w = gact(rv.w + bias2, gt);
      g2b[tid] = av;
    }
    __syncthreads();

    // ---- P6: layer-2 state update; commit x prefetch ----
    if (tid < HID) {
      float4 iv = g2b[tid], fv = g2b[tid + HID];
      float4 gv = g2b[tid + 2 * HID], ov = g2b[tid + 3 * HID];
      float4 c = c2s[tid];
      c.x = fmaf(fv.x, c.x, iv.x * gv.x);
      c.y = fmaf(fv.y, c.y, iv.y * gv.y);
      c.z = fmaf(fv.z, c.z, iv.z * gv.z);
      c.w = fmaf(fv.w, c.w, iv.w * gv.w);
      c2s[tid] = c;
      float4 h;
      h.x = ov.x * ftanh(c.x);
      h.y = ov.y * ftanh(c.y);
      h.z = ov.z * ftanh(c.z);
      h.w = ov.w * ftanh(c.w);
      h2f[tid] = h;
      hB2[0 * HB_STR + tid] = (_Float16)h.x;
      hB2[1 * HB_STR + tid] = (_Float16)h.y;
      hB2[2 * HB_STR + tid] = (_Float16)h.z;
      hB2[3 * HB_STR + tid] = (_Float16)h.w;
    } else if (((tid & ~3) == 128) && (t + 1) < T_LEN) {
      xb[(t + 1) & 1][tid & 3] = xpref;
    }
    __syncthreads();
  }
  if (tid < 64) store_out4(h2f, wo0, wo1, bo, tid, b0, outp, T_LEN - 1);
}

// ---------------------------------------------------------------------------
// Fallback (round-1, known-correct fp32 path)
// ---------------------------------------------------------------------------
__global__ void __launch_bounds__(512) transpose_w(
    const float* __restrict__ w1, const float* __restrict__ w2,
    const float* __restrict__ w3, float* __restrict__ o) {
  int m = blockIdx.y;
  const float* src = (m == 0) ? w1 : (m == 1) ? w2 : w3;
  float* dst = o + (size_t)m * G4 * HID;
  int idx = blockIdx.x * 512 + threadIdx.x;
  int j = idx >> 7;
  int k = idx & (HID - 1);
  dst[k * G4 + j] = src[idx];
}

__global__ void __launch_bounds__(512) lstm_fused(
    const float* __restrict__ xin, const float* __restrict__ Wih1,
    const float* __restrict__ bih1, const float* __restrict__ bhh1,
    const float* __restrict__ Whh1, const float* __restrict__ Wih2,
    const float* __restrict__ Whh2, int sk, int sj,
    const float* __restrict__ bih2, const float* __restrict__ bhh2,
    const float* __restrict__ Wout, const float* __restrict__ bout,
    float* __restrict__ outp) {
  __shared__ float4 h1buf[HID];
  __shared__ float4 h2buf[HID];
  __shared__ float4 g1[G4];
  __shared__ float4 g2[G4];
  __shared__ float xb[2][BCH];

  const int tid = threadIdx.x;
  const int b0 = blockIdx.x * BCH;
  const int gt = tid >> 7;

  float bias1 = bih1[tid] + bhh1[tid];
  float bias2 = bih2[tid] + bhh2[tid];
  float wi1 = Wih1[tid];
  float c1_0 = 0.f, c1_1 = 0.f, c1_2 = 0.f, c1_3 = 0.f;
  float c2_0 = 0.f, c2_1 = 0.f, c2_2 = 0.f, c2_3 = 0.f;
  float wo0 = 0.f, wo1 = 0.f, bo = 0.f;
  if (tid < 64) { wo0 = Wout[tid]; wo1 = Wout[tid + 64]; bo = bout[0]; }
  if (tid < HID) {
    h1buf[tid] = make_float4(0.f, 0.f, 0.f, 0.f);
    h2buf[tid] = make_float4(0.f, 0.f, 0.f, 0.f);
  }
  if (tid < BCH) xb[0][tid] = xin[(b0 + tid) * T_LEN];
  __syncthreads();

  const float* wp1  = Whh1 + tid * sj;
  const float* wp2  = Whh2 + tid * sj;
  const float* wpi2 = Wih2 + tid * sj;

  for (int t = 0; t < T_LEN; ++t) {
    float xpref = 0.f;
    if ((tid & ~3) == 128 && (t + 1) < T_LEN)
      xpref = xin[(b0 + (tid & 3)) * T_LEN + t + 1];

    if (tid < 64 && t > 0) store_out4(h2buf, wo0, wo1, bo, tid, b0, outp, t - 1);

    float xv0 = xb[t & 1][0], xv1 = xb[t & 1][1];
    float xv2 = xb[t & 1][2], xv3 = xb[t & 1][3];
    float a10 = fmaf(wi1, xv0, bias1);
    float a11 = fmaf(wi1, xv1, bias1);
    float a12 = fmaf(wi1, xv2, bias1);
    float a13 = fmaf(wi1, xv3, bias1);
    float a20 = bias2, a21 = bias2, a22 = bias2, a23 = bias2;
#pragma unroll 8
    for (int k = 0; k < HID; ++k) {
      float w1 = wp1[k * sk];
      float w2 = wp2[k * sk];
      float4 hv1 = h1buf[k];
      float4 hv2 = h2buf[k];
      a10 = fmaf(w1, hv1.x, a10);
      a11 = fmaf(w1, hv1.y, a11);
      a12 = fmaf(w1, hv1.z, a12);
      a13 = fmaf(w1, hv1.w, a13);
      a20 = fmaf(w2, hv2.x, a20);
      a21 = fmaf(w2, hv2.y, a21);
      a22 = fmaf(w2, hv2.z, a22);
      a23 = fmaf(w2, hv2.w, a23);
    }
    float4 A1;
    A1.x = gact(a10, gt); A1.y = gact(a11, gt);
    A1.z = gact(a12, gt); A1.w = gact(a13, gt);
    g1[tid] = A1;
    __syncthreads();

    if (tid < HID) {
      float4 iv = g1[tid], fv = g1[tid + HID];
      float4 gv = g1[tid + 2 * HID], ov = g1[tid + 3 * HID];
      c1_0 = fmaf(fv.x, c1_0, iv.x * gv.x);
      c1_1 = fmaf(fv.y, c1_1, iv.y * gv.y);
      c1_2 = fmaf(fv.z, c1_2, iv.z * gv.z);
      c1_3 = fmaf(fv.w, c1_3, iv.w * gv.w);
      float4 h;
      h.x = ov.x * ftanh(c1_0);
      h.y = ov.y * ftanh(c1_1);
      h.z = ov.z * ftanh(c1_2);
      h.w = ov.w * ftanh(c1_3);
      h1buf[tid] = h;
    }
    __syncthreads();

#pragma unroll 8
    for (int k = 0; k < HID; ++k) {
      float w = wpi2[k * sk];
      float4 hv = h1buf[k];
      a20 = fmaf(w, hv.x, a20);
      a21 = fmaf(w, hv.y, a21);
      a22 = fmaf(w, hv.z, a22);
      a23 = fmaf(w, hv.w, a23);
    }
    float4 A2;
    A2.x = gact(a20, gt); A2.y = gact(a21, gt);
    A2.z = gact(a22, gt); A2.w = gact(a23, gt);
    g2[tid] = A2;
    __syncthreads();

    if (tid < HID) {
      float4 iv = g2[tid], fv = g2[tid + HID];
      float4 gv = g2[tid + 2 * HID], ov = g2[tid + 3 * HID];
      c2_0 = fmaf(fv.x, c2_0, iv.x * gv.x);
      c2_1 = fmaf(fv.y, c2_1, iv.y * gv.y);
      c2_2 = fmaf(fv.z, c2_2, iv.z * gv.z);
      c2_3 = fmaf(fv.w, c2_3, iv.w * gv.w);
      float4 h;
      h.x = ov.x * ftanh(c2_0);
      h.y = ov.y * ftanh(c2_1);
      h.z = ov.z * ftanh(c2_2);
      h.w = ov.w * ftanh(c2_3);
      h2buf[tid] = h;
    } else if ((tid & ~3) == 128 && (t + 1) < T_LEN) {
      xb[(t + 1) & 1][tid & 3] = xpref;
    }
    __syncthreads();
  }
  if (tid < 64) store_out4(h2buf, wo0, wo1, bo, tid, b0, outp, T_LEN - 1);
}

extern "C" void kernel_launch(void* const* d_in, const int* in_sizes, int n_in,
                              void* d_out, int out_size, void* d_ws, size_t ws_size,
                              hipStream_t stream) {
  const float* xin  = (const float*)d_in[0];
  const float* Wih1 = (const float*)d_in[1];
  const float* Whh1 = (const float*)d_in[2];
  const float* bih1 = (const float*)d_in[3];
  const float* bhh1 = (const float*)d_in[4];
  const float* Wih2 = (const float*)d_in[5];
  const float* Whh2 = (const float*)d_in[6];
  const float* bih2 = (const float*)d_in[7];
  const float* bhh2 = (const float*)d_in[8];
  const float* Wout = (const float*)d_in[9];
  const float* bout = (const float*)d_in[10];
  float* outp = (float*)d_out;

  const size_t needFr = (size_t)3 * 8 * 16 * 64 * sizeof(uint4);  // 384 KB
  if (ws_size >= needFr) {
    uint4* wfrag = (uint4*)d_ws;
    pack_frag<<<96, 256, 0, stream>>>(Whh1, Whh2, Wih2, wfrag);
    lstm_mfma<<<NG, 512, 0, stream>>>(
        xin, Wih1, bih1, bhh1, wfrag, bih2, bhh2, Wout, bout, outp);
    return;
  }

  // fallback: round-1 fp32 kernel
  size_t need = (size_t)3 * G4 * HID * sizeof(float);
  if (ws_size >= need) {
    float* wt = (float*)d_ws;
    transpose_w<<<dim3(128, 3), 512, 0, stream>>>(Whh1, Wih2, Whh2, wt);
    lstm_fused<<<NG, 512, 0, stream>>>(
        xin, Wih1, bih1, bhh1,
        wt, wt + (size_t)G4 * HID, wt + (size_t)2 * G4 * HID, G4, 1,
        bih2, bhh2, Wout, bout, outp);
  } else {
    lstm_fused<<<NG, 512, 0, stream>>>(
        xin, Wih1, bih1, bhh1,
        Whh1, Wih2, Whh2, 1, HID,
        bih2, bhh2, Wout, bout, outp);
  }
}